// Round 6
// baseline (610.997 us; speedup 1.0000x reference)
//
#include <hip/hip_runtime.h>
#include <hip/hip_fp16.h>

#define NN 8192
#define MM 8192
#define FD 128
#define EDm 128
#define HD 64
#define NH 4

#define MSPLIT 4
#define MRANGE (MM / MSPLIT)   // 2048

typedef float f32x4 __attribute__((ext_vector_type(4)));
typedef _Float16 h16x8 __attribute__((ext_vector_type(8)));
typedef _Float16 h16x4 __attribute__((ext_vector_type(4)));
typedef int i32x4 __attribute__((ext_vector_type(4)));
typedef unsigned int u32;

// vf[h][f] = sum_d Wf[h][f][d] * a[h][d]
__global__ void k_vf(const float* __restrict__ Wf, const float* __restrict__ a,
                     float* __restrict__ vf) {
  int t = threadIdx.x;  // 512
  int h = t >> 7, f = t & 127;
  const float* w = Wf + (size_t)(h * FD + f) * HD;
  const float* av = a + h * HD;
  float s = 0.f;
#pragma unroll
  for (int d = 0; d < HD; ++d) s += w[d] * av[d];
  vf[h * FD + f] = s;
}

// esrc[h][n] = F0[n,:] . vf[h,:]
__global__ void k_esrc(const float* __restrict__ F0, const float* __restrict__ vf,
                       float* __restrict__ esrc) {
  int t = blockIdx.x * blockDim.x + threadIdx.x;  // 32768
  int n = t >> 2, h = t & 3;
  const float4* fr = (const float4*)(F0 + (size_t)n * FD);
  const float4* vr = (const float4*)(vf + h * FD);
  float s = 0.f;
#pragma unroll
  for (int i = 0; i < FD / 4; ++i) {
    float4 x = fr[i], y = vr[i];
    s += x.x * y.x + x.y * y.y + x.z * y.z + x.w * y.w;
  }
  esrc[h * NN + n] = s;
}

// E1 fp32 -> E1T fp16 [h][d][m]; edh = e^d, ed2h = e^{0.2 d} fp16 tables.
__global__ void k_e1(const float* __restrict__ E0, const float* __restrict__ We,
                     const float* __restrict__ a, _Float16* __restrict__ E1T,
                     _Float16* __restrict__ edh, _Float16* __restrict__ ed2h) {
  int wid = (blockIdx.x * blockDim.x + threadIdx.x) >> 6;
  int lane = threadIdx.x & 63;
  int h = wid >> 11;
  int mg = wid & 2047;
  int m = mg * 4;
  const float* we = We + (size_t)h * EDm * HD + lane;
  const float* e0r = E0 + (size_t)m * EDm;
  float a0 = 0.f, a1 = 0.f, a2 = 0.f, a3 = 0.f;
#pragma unroll 4
  for (int e = 0; e < EDm; ++e) {
    float wv = we[e * HD];
    a0 += e0r[e] * wv;
    a1 += e0r[EDm + e] * wv;
    a2 += e0r[2 * EDm + e] * wv;
    a3 += e0r[3 * EDm + e] * wv;
  }
  h16x4 hv = {(_Float16)a0, (_Float16)a1, (_Float16)a2, (_Float16)a3};
  *(h16x4*)(E1T + (size_t)(h * HD + lane) * MM + m) = hv;
  float av = a[h * HD + lane];
  float d0 = a0 * av, d1 = a1 * av, d2 = a2 * av, d3 = a3 * av;
#pragma unroll
  for (int o = 32; o; o >>= 1) {
    d0 += __shfl_xor(d0, o);
    d1 += __shfl_xor(d1, o);
    d2 += __shfl_xor(d2, o);
    d3 += __shfl_xor(d3, o);
  }
  if (lane == 0) {
    const float L2E = 1.4426950408889634f;
    edh[h * MM + m + 0] = (_Float16)exp2f(d0 * L2E);
    edh[h * MM + m + 1] = (_Float16)exp2f(d1 * L2E);
    edh[h * MM + m + 2] = (_Float16)exp2f(d2 * L2E);
    edh[h * MM + m + 3] = (_Float16)exp2f(d3 * L2E);
    ed2h[h * MM + m + 0] = (_Float16)exp2f(0.2f * d0 * L2E);
    ed2h[h * MM + m + 1] = (_Float16)exp2f(0.2f * d1 * L2E);
    ed2h[h * MM + m + 2] = (_Float16)exp2f(0.2f * d2 * L2E);
    ed2h[h * MM + m + 3] = (_Float16)exp2f(0.2f * d3 * L2E);
  }
}

// a,b in {0,1}: returns half-mask pair (a ? 0xffff : 0) | (b ? 0xffff0000 : 0)
__device__ __forceinline__ u32 hm2(int a, int b) {
  return ((u32)a | ((u32)b << 16)) * 0xffffu;
}

// Main: 1024 blocks x 256 thr, ZERO barriers / ZERO LDS in the loop.
// Wave = 32 n-rows x 1 head x 2048-m split. Masks loaded per-lane directly
// from A in MFMA A-operand layout (lane col = n-row, quad = k-chunk).
// Block = 4 heads of same tile -> A lines shared via L1. split = b&3.
__global__ __launch_bounds__(256) void k_main(
    const int* __restrict__ A, const _Float16* __restrict__ E1T,
    const float* __restrict__ esrc, const _Float16* __restrict__ edh,
    const _Float16* __restrict__ ed2h, float* __restrict__ pnum,
    float* __restrict__ pden) {
  const int t = threadIdx.x;
  const int lane = t & 63;
  const int h = t >> 6;              // head (wave index in block)
  const int col = lane & 15;
  const int quad = lane >> 4;

  const int b = blockIdx.x;
  const int split = b & 3;           // XCD pair {s, s+4} per split
  const int ntile = b >> 2;
  const int n0 = ntile * 32;
  const int m0 = split * MRANGE;
  const float L2E = 1.4426950408889634f;

  float s0 = esrc[h * NN + n0 + col];
  float s1 = esrc[h * NN + n0 + 16 + col];
  _Float16 e80 = (_Float16)exp2f(0.8f * s0 * L2E);
  _Float16 e81 = (_Float16)exp2f(0.8f * s1 * L2E);
  h16x8 es80 = {e80, e80, e80, e80, e80, e80, e80, e80};
  h16x8 es81 = {e81, e81, e81, e81, e81, e81, e81, e81};

  f32x4 acc[2][4] = {};
  f32x4 accd[2] = {};
  const h16x8 ones = {(_Float16)1.f, (_Float16)1.f, (_Float16)1.f, (_Float16)1.f,
                      (_Float16)1.f, (_Float16)1.f, (_Float16)1.f, (_Float16)1.f};

  // Per-lane pointers in MFMA A-operand layout.
  const int* ap0 = A + (size_t)(n0 + col) * MM + m0 + quad * 8;       // rows 0-15
  const int* ap1 = ap0 + (size_t)16 * MM;                             // rows 16-31
  const _Float16* edp = edh + (size_t)h * MM + m0 + quad * 8;
  const _Float16* e2p = ed2h + (size_t)h * MM + m0 + quad * 8;
  const _Float16* bq = E1T + (size_t)(h * HD + col) * MM + m0 + quad * 8;

  for (int k = 0; k < MRANGE; k += 32) {
    // loads first: masks (scattered, L1/L2-shared across the 4 head-waves),
    // exp tables (quad-broadcast), B-frags (L2-resident E1T slice)
    i32x4 a00 = *(const i32x4*)(ap0 + k);
    i32x4 a01 = *(const i32x4*)(ap0 + k + 4);
    i32x4 a10 = *(const i32x4*)(ap1 + k);
    i32x4 a11 = *(const i32x4*)(ap1 + k + 4);
    h16x8 edv = *(const h16x8*)(edp + k);
    h16x8 e2v = *(const h16x8*)(e2p + k);
    h16x8 bf0 = *(const h16x8*)(bq + k);
    h16x8 bf1 = *(const h16x8*)(bq + (size_t)16 * MM + k);
    h16x8 bf2 = *(const h16x8*)(bq + (size_t)32 * MM + k);
    h16x8 bf3 = *(const h16x8*)(bq + (size_t)48 * MM + k);

    union { h16x8 v; uint4 u; } w0, w1;
    w0.v = __builtin_elementwise_max(edv * es80, e2v);
    w1.v = __builtin_elementwise_max(edv * es81, e2v);
    w0.u.x &= hm2(a00.x, a00.y);
    w0.u.y &= hm2(a00.z, a00.w);
    w0.u.z &= hm2(a01.x, a01.y);
    w0.u.w &= hm2(a01.z, a01.w);
    w1.u.x &= hm2(a10.x, a10.y);
    w1.u.y &= hm2(a10.z, a10.w);
    w1.u.z &= hm2(a11.x, a11.y);
    w1.u.w &= hm2(a11.z, a11.w);

    acc[0][0] = __builtin_amdgcn_mfma_f32_16x16x32_f16(w0.v, bf0, acc[0][0], 0, 0, 0);
    acc[1][0] = __builtin_amdgcn_mfma_f32_16x16x32_f16(w1.v, bf0, acc[1][0], 0, 0, 0);
    acc[0][1] = __builtin_amdgcn_mfma_f32_16x16x32_f16(w0.v, bf1, acc[0][1], 0, 0, 0);
    acc[1][1] = __builtin_amdgcn_mfma_f32_16x16x32_f16(w1.v, bf1, acc[1][1], 0, 0, 0);
    acc[0][2] = __builtin_amdgcn_mfma_f32_16x16x32_f16(w0.v, bf2, acc[0][2], 0, 0, 0);
    acc[1][2] = __builtin_amdgcn_mfma_f32_16x16x32_f16(w1.v, bf2, acc[1][2], 0, 0, 0);
    acc[0][3] = __builtin_amdgcn_mfma_f32_16x16x32_f16(w0.v, bf3, acc[0][3], 0, 0, 0);
    acc[1][3] = __builtin_amdgcn_mfma_f32_16x16x32_f16(w1.v, bf3, acc[1][3], 0, 0, 0);
    accd[0] = __builtin_amdgcn_mfma_f32_16x16x32_f16(w0.v, ones, accd[0], 0, 0, 0);
    accd[1] = __builtin_amdgcn_mfma_f32_16x16x32_f16(w1.v, ones, accd[1], 0, 0, 0);
  }

  // Epilogue: raw partial stores (no LDS). C/D layout: d = dt*16+col,
  // n = rt*16 + quad*4 + r2. Per store inst: 4 segments of 64B — fine.
  float* pn = pnum + (size_t)(split * NH + h) * NN * HD;
  float* pd = pden + (size_t)(split * NH + h) * NN;
#pragma unroll
  for (int rt = 0; rt < 2; ++rt) {
#pragma unroll
    for (int dt = 0; dt < 4; ++dt)
#pragma unroll
      for (int r2 = 0; r2 < 4; ++r2) {
        int row = n0 + rt * 16 + quad * 4 + r2;
        pn[(size_t)row * HD + dt * 16 + col] = acc[rt][dt][r2];
      }
    if (col == 0) {
#pragma unroll
      for (int r2 = 0; r2 < 4; ++r2)
        pd[n0 + rt * 16 + quad * 4 + r2] = accd[rt][r2];
    }
  }
}

// Combine splits, mean over heads, row softmax. Wave per n-row.
__global__ void k_comb(const float* __restrict__ pnum, const float* __restrict__ pden,
                       float* __restrict__ out) {
  int t = threadIdx.x;
  int lane = t & 63, w = t >> 6;
  int n = blockIdx.x * 4 + w;
  float v = 0.f;
#pragma unroll
  for (int h = 0; h < NH; ++h) {
    float num = 0.f, den = 0.f;
#pragma unroll
    for (int s = 0; s < MSPLIT; ++s) {
      num += pnum[((size_t)(s * NH + h) * NN + n) * HD + lane];
      den += pden[(size_t)(s * NH + h) * NN + n];
    }
    v += num / den;
  }
  v *= 0.25f;
  float mx = v;
#pragma unroll
  for (int o = 32; o; o >>= 1) mx = fmaxf(mx, __shfl_xor(mx, o));
  const float L2E = 1.4426950408889634f;
  float p = exp2f((v - mx) * L2E);
  float sm = p;
#pragma unroll
  for (int o = 32; o; o >>= 1) sm += __shfl_xor(sm, o);
  out[(size_t)n * HD + lane] = p / sm;
}

extern "C" void kernel_launch(void* const* d_in, const int* in_sizes, int n_in,
                              void* d_out, int out_size, void* d_ws, size_t ws_size,
                              hipStream_t stream) {
  const float* F0 = (const float*)d_in[0];
  const float* E0 = (const float*)d_in[1];
  const int* A = (const int*)d_in[2];
  const float* Wf = (const float*)d_in[3];
  const float* We = (const float*)d_in[4];
  const float* a = (const float*)d_in[5];
  float* out = (float*)d_out;

  char* w = (char*)d_ws;
  float* esrc = (float*)w;        w += (size_t)NH * NN * 4;
  _Float16* edh = (_Float16*)w;   w += (size_t)NH * MM * 2;
  _Float16* ed2h = (_Float16*)w;  w += (size_t)NH * MM * 2;
  float* vf = (float*)w;          w += (size_t)NH * FD * 4;
  _Float16* E1T = (_Float16*)w;   w += (size_t)NH * HD * MM * 2;
  float* pnum = (float*)w;        w += (size_t)MSPLIT * NH * NN * HD * 4;
  float* pden = (float*)w;        w += (size_t)MSPLIT * NH * NN * 4;

  k_vf<<<1, 512, 0, stream>>>(Wf, a, vf);
  k_esrc<<<(NH * NN) / 256, 256, 0, stream>>>(F0, vf, esrc);
  k_e1<<<(NH * MM / 4) / 4, 256, 0, stream>>>(E0, We, a, E1T, edh, ed2h);
  k_main<<<(NN / 32) * MSPLIT, 256, 0, stream>>>(A, E1T, esrc, edh, ed2h, pnum, pden);
  k_comb<<<NN / 4, 256, 0, stream>>>(pnum, pden, out);
}

// Round 7
// 587.241 us; speedup vs baseline: 1.0405x; 1.0405x over previous
//
#include <hip/hip_runtime.h>
#include <hip/hip_fp16.h>

#define NN 8192
#define MM 8192
#define FD 128
#define EDm 128
#define HD 64
#define NH 4
#define NTILE 32

typedef float f32x4 __attribute__((ext_vector_type(4)));
typedef _Float16 h16x8 __attribute__((ext_vector_type(8)));
typedef _Float16 h16x4 __attribute__((ext_vector_type(4)));
typedef unsigned int u32;

// vf[h][f] = sum_d Wf[h][f][d] * a[h][d]
__global__ void k_vf(const float* __restrict__ Wf, const float* __restrict__ a,
                     float* __restrict__ vf) {
  int t = threadIdx.x;  // 512
  int h = t >> 7, f = t & 127;
  const float* w = Wf + (size_t)(h * FD + f) * HD;
  const float* av = a + h * HD;
  float s = 0.f;
#pragma unroll
  for (int d = 0; d < HD; ++d) s += w[d] * av[d];
  vf[h * FD + f] = s;
}

// esrc[h][n] = F0[n,:] . vf[h,:]
__global__ void k_esrc(const float* __restrict__ F0, const float* __restrict__ vf,
                       float* __restrict__ esrc) {
  int t = blockIdx.x * blockDim.x + threadIdx.x;  // 32768
  int n = t >> 2, h = t & 3;
  const float4* fr = (const float4*)(F0 + (size_t)n * FD);
  const float4* vr = (const float4*)(vf + h * FD);
  float s = 0.f;
#pragma unroll
  for (int i = 0; i < FD / 4; ++i) {
    float4 x = fr[i], y = vr[i];
    s += x.x * y.x + x.y * y.y + x.z * y.z + x.w * y.w;
  }
  esrc[h * NN + n] = s;
}

// E1 fp32 -> E1T fp16 [h][d][m]; edh = e^d, ed2h = e^{0.2 d} fp16 tables.
__global__ void k_e1(const float* __restrict__ E0, const float* __restrict__ We,
                     const float* __restrict__ a, _Float16* __restrict__ E1T,
                     _Float16* __restrict__ edh, _Float16* __restrict__ ed2h) {
  int wid = (blockIdx.x * blockDim.x + threadIdx.x) >> 6;
  int lane = threadIdx.x & 63;
  int h = wid >> 11;
  int mg = wid & 2047;
  int m = mg * 4;
  const float* we = We + (size_t)h * EDm * HD + lane;
  const float* e0r = E0 + (size_t)m * EDm;
  float a0 = 0.f, a1 = 0.f, a2 = 0.f, a3 = 0.f;
#pragma unroll 4
  for (int e = 0; e < EDm; ++e) {
    float wv = we[e * HD];
    a0 += e0r[e] * wv;
    a1 += e0r[EDm + e] * wv;
    a2 += e0r[2 * EDm + e] * wv;
    a3 += e0r[3 * EDm + e] * wv;
  }
  h16x4 hv = {(_Float16)a0, (_Float16)a1, (_Float16)a2, (_Float16)a3};
  *(h16x4*)(E1T + (size_t)(h * HD + lane) * MM + m) = hv;
  float av = a[h * HD + lane];
  float d0 = a0 * av, d1 = a1 * av, d2 = a2 * av, d3 = a3 * av;
#pragma unroll
  for (int o = 32; o; o >>= 1) {
    d0 += __shfl_xor(d0, o);
    d1 += __shfl_xor(d1, o);
    d2 += __shfl_xor(d2, o);
    d3 += __shfl_xor(d3, o);
  }
  if (lane == 0) {
    const float L2E = 1.4426950408889634f;
    edh[h * MM + m + 0] = (_Float16)exp2f(d0 * L2E);
    edh[h * MM + m + 1] = (_Float16)exp2f(d1 * L2E);
    edh[h * MM + m + 2] = (_Float16)exp2f(d2 * L2E);
    edh[h * MM + m + 3] = (_Float16)exp2f(d3 * L2E);
    ed2h[h * MM + m + 0] = (_Float16)exp2f(0.2f * d0 * L2E);
    ed2h[h * MM + m + 1] = (_Float16)exp2f(0.2f * d1 * L2E);
    ed2h[h * MM + m + 2] = (_Float16)exp2f(0.2f * d2 * L2E);
    ed2h[h * MM + m + 3] = (_Float16)exp2f(0.2f * d3 * L2E);
  }
}

// A (256 MB int 0/1) -> bitmask Abt[m/32][n] (8 MB). Wave per row, ballot.
__global__ void k_abits(const int* __restrict__ A, u32* __restrict__ Abt) {
  int n = blockIdx.x * 4 + (threadIdx.x >> 6);
  int lane = threadIdx.x & 63;
  const int* ar = A + (size_t)n * MM + lane;
#pragma unroll 4
  for (int s = 0; s < 128; ++s) {
    int v = __builtin_nontemporal_load(ar + s * 64);
    unsigned long long m = __ballot(v > 0);
    if (lane == 0) Abt[(size_t)(2 * s) * NN + n] = (u32)m;
    else if (lane == 32) Abt[(size_t)(2 * s + 1) * NN + n] = (u32)(m >> 32);
  }
}

// E1T [h][d][m] -> Bp[h][mc][dt][lane] MFMA-B fragment order (lane-coalesced).
__global__ void k_pack(const _Float16* __restrict__ E1T, uint4* __restrict__ Bp) {
  int t = threadIdx.x;               // 256
  int b = blockIdx.x;                // 1024
  int mc = b & 255, h = b >> 8;
  int lane = t & 63, dt = t >> 6;
  const _Float16* src = E1T + (size_t)(h * 64 + dt * 16 + (lane & 15)) * MM +
                        mc * 32 + (lane >> 4) * 8;
  Bp[(((size_t)h * 256 + mc) * 4 + dt) * 64 + lane] = *(const uint4*)src;
}

__device__ __forceinline__ u32 hm2(int a, int b) {
  return ((u32)a | ((u32)b << 16)) * 0xffffu;
}

// Main: 256 blocks x 1024 thr (16 waves = 4 heads x 4 m-quarters), barrier-free
// loop, all loads coalesced/broadcast. In-block reduction + softmax -> out.
__global__ __launch_bounds__(1024, 4) void k_main(
    const u32* __restrict__ Abt, const uint4* __restrict__ Bp,
    const float* __restrict__ esrc, const _Float16* __restrict__ edh,
    const _Float16* __restrict__ ed2h, float* __restrict__ out) {
  __shared__ __align__(16) char smem[45568];
  uint4* LUT = (uint4*)smem;                  // 256 x 16B = 4 KB
  float* Hsum = (float*)(smem + 4096);        // [4][32][64] = 32 KB
  float* Dsum = (float*)(smem + 36864);       // [4][32] = 512 B
  float* hp = (float*)(smem + 37376);         // [32][64] = 8 KB

  const int t = threadIdx.x;
  const int lane = t & 63;
  const int wv = t >> 6;       // 0..15
  const int h = wv & 3;        // head
  const int q = wv >> 2;       // m-quarter (2048 m each)
  const int col = lane & 15;
  const int quad = lane >> 4;
  const int qs = quad * 8;
  const int n0 = blockIdx.x * NTILE;
  const float L2E = 1.4426950408889634f;

  if (t < 256) {
    uint4 e;
    e.x = hm2((t >> 0) & 1, (t >> 1) & 1);
    e.y = hm2((t >> 2) & 1, (t >> 3) & 1);
    e.z = hm2((t >> 4) & 1, (t >> 5) & 1);
    e.w = hm2((t >> 6) & 1, (t >> 7) & 1);
    LUT[t] = e;
  }
  for (int i = t; i < 8320; i += 1024) ((float*)(smem + 4096))[i] = 0.f;
  __syncthreads();

  float s0 = esrc[h * NN + n0 + col];
  float s1 = esrc[h * NN + n0 + 16 + col];
  _Float16 e80 = (_Float16)exp2f(0.8f * s0 * L2E);
  _Float16 e81 = (_Float16)exp2f(0.8f * s1 * L2E);
  h16x8 es80 = {e80, e80, e80, e80, e80, e80, e80, e80};
  h16x8 es81 = {e81, e81, e81, e81, e81, e81, e81, e81};

  f32x4 acc[2][4] = {};
  f32x4 accd[2] = {};
  const h16x8 ones = {(_Float16)1.f, (_Float16)1.f, (_Float16)1.f, (_Float16)1.f,
                      (_Float16)1.f, (_Float16)1.f, (_Float16)1.f, (_Float16)1.f};

  const u32* ab0 = Abt + (size_t)(q * 64) * NN + n0 + col;        // +it*NN
  const u32* ab1 = ab0 + 16;
  const _Float16* edp = edh + (size_t)h * MM + q * 2048 + qs;     // +it*32
  const _Float16* e2p = ed2h + (size_t)h * MM + q * 2048 + qs;
  const uint4* bp = Bp + ((size_t)h * 256 + q * 64) * 256 + lane; // +it*256+dt*64

  for (int it = 0; it < 64; ++it) {
    u32 aw0 = ab0[(size_t)it * NN];       // 16 consecutive dwords, quad-bcast
    u32 aw1 = ab1[(size_t)it * NN];
    uint4 m0 = LUT[(aw0 >> qs) & 0xff];
    uint4 m1 = LUT[(aw1 >> qs) & 0xff];
    h16x8 edv = *(const h16x8*)(edp + it * 32);
    h16x8 e2v = *(const h16x8*)(e2p + it * 32);
    union { h16x8 v; uint4 u; } w0, w1, b0, b1, b2, b3;
    b0.u = bp[it * 256];                  // lane-coalesced dwordx4 (L2)
    b1.u = bp[it * 256 + 64];
    b2.u = bp[it * 256 + 128];
    b3.u = bp[it * 256 + 192];
    w0.v = __builtin_elementwise_max(edv * es80, e2v);
    w1.v = __builtin_elementwise_max(edv * es81, e2v);
    w0.u.x &= m0.x; w0.u.y &= m0.y; w0.u.z &= m0.z; w0.u.w &= m0.w;
    w1.u.x &= m1.x; w1.u.y &= m1.y; w1.u.z &= m1.z; w1.u.w &= m1.w;

    acc[0][0] = __builtin_amdgcn_mfma_f32_16x16x32_f16(w0.v, b0.v, acc[0][0], 0, 0, 0);
    acc[1][0] = __builtin_amdgcn_mfma_f32_16x16x32_f16(w1.v, b0.v, acc[1][0], 0, 0, 0);
    acc[0][1] = __builtin_amdgcn_mfma_f32_16x16x32_f16(w0.v, b1.v, acc[0][1], 0, 0, 0);
    acc[1][1] = __builtin_amdgcn_mfma_f32_16x16x32_f16(w1.v, b1.v, acc[1][1], 0, 0, 0);
    acc[0][2] = __builtin_amdgcn_mfma_f32_16x16x32_f16(w0.v, b2.v, acc[0][2], 0, 0, 0);
    acc[1][2] = __builtin_amdgcn_mfma_f32_16x16x32_f16(w1.v, b2.v, acc[1][2], 0, 0, 0);
    acc[0][3] = __builtin_amdgcn_mfma_f32_16x16x32_f16(w0.v, b3.v, acc[0][3], 0, 0, 0);
    acc[1][3] = __builtin_amdgcn_mfma_f32_16x16x32_f16(w1.v, b3.v, acc[1][3], 0, 0, 0);
    accd[0] = __builtin_amdgcn_mfma_f32_16x16x32_f16(w0.v, ones, accd[0], 0, 0, 0);
    accd[1] = __builtin_amdgcn_mfma_f32_16x16x32_f16(w1.v, ones, accd[1], 0, 0, 0);
  }

  // Reduce quarters/rows via LDS float atomics (ds_add), once per block.
  float* Hh = Hsum + h * 2048;
#pragma unroll
  for (int rt = 0; rt < 2; ++rt) {
#pragma unroll
    for (int dt = 0; dt < 4; ++dt)
#pragma unroll
      for (int r2 = 0; r2 < 4; ++r2)
        atomicAdd(&Hh[(rt * 16 + quad * 4 + r2) * 64 + dt * 16 + col],
                  acc[rt][dt][r2]);
    if (col == 0) {
#pragma unroll
      for (int r2 = 0; r2 < 4; ++r2)
        atomicAdd(&Dsum[h * 32 + rt * 16 + quad * 4 + r2], accd[rt][r2]);
    }
  }
  __syncthreads();

  // Head mean with per-head denom; then per-row softmax.
  for (int i = t; i < 2048; i += 1024) {
    int r = i >> 6;
    float v = 0.f;
#pragma unroll
    for (int hh = 0; hh < 4; ++hh) v += Hsum[hh * 2048 + i] / Dsum[hh * 32 + r];
    hp[i] = 0.25f * v;
  }
  __syncthreads();

#pragma unroll
  for (int i = 0; i < 2; ++i) {
    int r = wv * 2 + i;
    float v = hp[r * 64 + lane];
    float mx = v;
#pragma unroll
    for (int o = 32; o; o >>= 1) mx = fmaxf(mx, __shfl_xor(mx, o));
    float p = exp2f((v - mx) * L2E);
    float sm = p;
#pragma unroll
    for (int o = 32; o; o >>= 1) sm += __shfl_xor(sm, o);
    out[(size_t)(n0 + r) * HD + lane] = p / sm;
  }
}

extern "C" void kernel_launch(void* const* d_in, const int* in_sizes, int n_in,
                              void* d_out, int out_size, void* d_ws, size_t ws_size,
                              hipStream_t stream) {
  const float* F0 = (const float*)d_in[0];
  const float* E0 = (const float*)d_in[1];
  const int* A = (const int*)d_in[2];
  const float* Wf = (const float*)d_in[3];
  const float* We = (const float*)d_in[4];
  const float* a = (const float*)d_in[5];
  float* out = (float*)d_out;

  char* w = (char*)d_ws;
  float* esrc = (float*)w;        w += (size_t)NH * NN * 4;
  _Float16* edh = (_Float16*)w;   w += (size_t)NH * MM * 2;
  _Float16* ed2h = (_Float16*)w;  w += (size_t)NH * MM * 2;
  float* vf = (float*)w;          w += (size_t)NH * FD * 4;
  _Float16* E1T = (_Float16*)w;   w += (size_t)NH * HD * MM * 2;
  uint4* Bp = (uint4*)w;          w += (size_t)NH * HD * MM * 2;
  u32* Abt = (u32*)w;             w += (size_t)(MM / 32) * NN * 4;

  k_vf<<<1, 512, 0, stream>>>(Wf, a, vf);
  k_esrc<<<(NH * NN) / 256, 256, 0, stream>>>(F0, vf, esrc);
  k_e1<<<(NH * MM / 4) / 4, 256, 0, stream>>>(E0, We, a, E1T, edh, ed2h);
  k_abits<<<NN / 4, 256, 0, stream>>>(A, Abt);
  k_pack<<<NH * 256, 256, 0, stream>>>(E1T, Bp);
  k_main<<<NN / NTILE, 1024, 0, stream>>>(Abt, Bp, esrc, edh, ed2h, out);
}

// Round 8
// 560.279 us; speedup vs baseline: 1.0905x; 1.0481x over previous
//
#include <hip/hip_runtime.h>
#include <hip/hip_fp16.h>

#define NN 8192
#define MM 8192
#define FD 128
#define EDm 128
#define HD 64
#define NH 4
#define NTILE 32

typedef float f32x4 __attribute__((ext_vector_type(4)));
typedef _Float16 h16x8 __attribute__((ext_vector_type(8)));
typedef _Float16 h16x4 __attribute__((ext_vector_type(4)));
typedef unsigned int u32;

// vf[h][f] = sum_d Wf[h][f][d] * a[h][d]
__global__ void k_vf(const float* __restrict__ Wf, const float* __restrict__ a,
                     float* __restrict__ vf) {
  int t = threadIdx.x;  // 512
  int h = t >> 7, f = t & 127;
  const float* w = Wf + (size_t)(h * FD + f) * HD;
  const float* av = a + h * HD;
  float s = 0.f;
#pragma unroll
  for (int d = 0; d < HD; ++d) s += w[d] * av[d];
  vf[h * FD + f] = s;
}

// esrc[h][n] = F0[n,:] . vf[h,:]
__global__ void k_esrc(const float* __restrict__ F0, const float* __restrict__ vf,
                       float* __restrict__ esrc) {
  int t = blockIdx.x * blockDim.x + threadIdx.x;  // 32768
  int n = t >> 2, h = t & 3;
  const float4* fr = (const float4*)(F0 + (size_t)n * FD);
  const float4* vr = (const float4*)(vf + h * FD);
  float s = 0.f;
#pragma unroll
  for (int i = 0; i < FD / 4; ++i) {
    float4 x = fr[i], y = vr[i];
    s += x.x * y.x + x.y * y.y + x.z * y.z + x.w * y.w;
  }
  esrc[h * NN + n] = s;
}

// E1 fp32 -> E1T fp16 [h][d][m]; edh = e^d, ed2h = e^{0.2 d} fp16 tables.
__global__ void k_e1(const float* __restrict__ E0, const float* __restrict__ We,
                     const float* __restrict__ a, _Float16* __restrict__ E1T,
                     _Float16* __restrict__ edh, _Float16* __restrict__ ed2h) {
  int wid = (blockIdx.x * blockDim.x + threadIdx.x) >> 6;
  int lane = threadIdx.x & 63;
  int h = wid >> 11;
  int mg = wid & 2047;
  int m = mg * 4;
  const float* we = We + (size_t)h * EDm * HD + lane;
  const float* e0r = E0 + (size_t)m * EDm;
  float a0 = 0.f, a1 = 0.f, a2 = 0.f, a3 = 0.f;
#pragma unroll 4
  for (int e = 0; e < EDm; ++e) {
    float wv = we[e * HD];
    a0 += e0r[e] * wv;
    a1 += e0r[EDm + e] * wv;
    a2 += e0r[2 * EDm + e] * wv;
    a3 += e0r[3 * EDm + e] * wv;
  }
  h16x4 hv = {(_Float16)a0, (_Float16)a1, (_Float16)a2, (_Float16)a3};
  *(h16x4*)(E1T + (size_t)(h * HD + lane) * MM + m) = hv;
  float av = a[h * HD + lane];
  float d0 = a0 * av, d1 = a1 * av, d2 = a2 * av, d3 = a3 * av;
#pragma unroll
  for (int o = 32; o; o >>= 1) {
    d0 += __shfl_xor(d0, o);
    d1 += __shfl_xor(d1, o);
    d2 += __shfl_xor(d2, o);
    d3 += __shfl_xor(d3, o);
  }
  if (lane == 0) {
    const float L2E = 1.4426950408889634f;
    edh[h * MM + m + 0] = (_Float16)exp2f(d0 * L2E);
    edh[h * MM + m + 1] = (_Float16)exp2f(d1 * L2E);
    edh[h * MM + m + 2] = (_Float16)exp2f(d2 * L2E);
    edh[h * MM + m + 3] = (_Float16)exp2f(d3 * L2E);
    ed2h[h * MM + m + 0] = (_Float16)exp2f(0.2f * d0 * L2E);
    ed2h[h * MM + m + 1] = (_Float16)exp2f(0.2f * d1 * L2E);
    ed2h[h * MM + m + 2] = (_Float16)exp2f(0.2f * d2 * L2E);
    ed2h[h * MM + m + 3] = (_Float16)exp2f(0.2f * d3 * L2E);
  }
}

// A (256 MB int 0/1) -> bitmask Abt[m/32][n] (8 MB). Wave per row, ballot.
__global__ void k_abits(const int* __restrict__ A, u32* __restrict__ Abt) {
  int n = blockIdx.x * 4 + (threadIdx.x >> 6);
  int lane = threadIdx.x & 63;
  const int* ar = A + (size_t)n * MM + lane;
#pragma unroll 4
  for (int s = 0; s < 128; ++s) {
    int v = __builtin_nontemporal_load(ar + s * 64);
    unsigned long long m = __ballot(v > 0);
    if (lane == 0) Abt[(size_t)(2 * s) * NN + n] = (u32)m;
    else if (lane == 32) Abt[(size_t)(2 * s + 1) * NN + n] = (u32)(m >> 32);
  }
}

// E1T [h][d][m] -> Bp[h][mc][dt][lane] MFMA-B fragment order (lane-coalesced).
__global__ void k_pack(const _Float16* __restrict__ E1T, uint4* __restrict__ Bp) {
  int t = threadIdx.x;               // 256
  int b = blockIdx.x;                // 1024
  int mc = b & 255, h = b >> 8;
  int lane = t & 63, dt = t >> 6;
  const _Float16* src = E1T + (size_t)(h * 64 + dt * 16 + (lane & 15)) * MM +
                        mc * 32 + (lane >> 4) * 8;
  Bp[(((size_t)h * 256 + mc) * 4 + dt) * 64 + lane] = *(const uint4*)src;
}

__device__ __forceinline__ u32 hm2(int a, int b) {
  return ((u32)a | ((u32)b << 16)) * 0xffffu;
}

// Main: 256 blocks x 1024 thr (16 waves = 4 heads x 4 m-quarters), barrier-free
// loop, all loads coalesced/broadcast, 1-iter register pipeline (loads for
// iter k+1 issued before consuming iter k). In-block reduce + softmax -> out.
__global__ __launch_bounds__(1024, 4) void k_main(
    const u32* __restrict__ Abt, const uint4* __restrict__ Bp,
    const float* __restrict__ esrc, const _Float16* __restrict__ edh,
    const _Float16* __restrict__ ed2h, float* __restrict__ out) {
  __shared__ __align__(16) char smem[45568];
  uint4* LUT = (uint4*)smem;                  // 256 x 16B = 4 KB
  float* Hsum = (float*)(smem + 4096);        // [4][32][64] = 32 KB
  float* Dsum = (float*)(smem + 36864);       // [4][32] = 512 B
  float* hp = (float*)(smem + 37376);         // [32][64] = 8 KB

  const int t = threadIdx.x;
  const int lane = t & 63;
  const int wv = t >> 6;       // 0..15
  const int h = wv & 3;        // head
  const int q = wv >> 2;       // m-quarter (2048 m each)
  const int col = lane & 15;
  const int quad = lane >> 4;
  const int qs = quad * 8;
  const int n0 = blockIdx.x * NTILE;
  const float L2E = 1.4426950408889634f;

  if (t < 256) {
    uint4 e;
    e.x = hm2((t >> 0) & 1, (t >> 1) & 1);
    e.y = hm2((t >> 2) & 1, (t >> 3) & 1);
    e.z = hm2((t >> 4) & 1, (t >> 5) & 1);
    e.w = hm2((t >> 6) & 1, (t >> 7) & 1);
    LUT[t] = e;
  }
  for (int i = t; i < 8320; i += 1024) ((float*)(smem + 4096))[i] = 0.f;
  __syncthreads();

  float s0 = esrc[h * NN + n0 + col];
  float s1 = esrc[h * NN + n0 + 16 + col];
  _Float16 e80 = (_Float16)exp2f(0.8f * s0 * L2E);
  _Float16 e81 = (_Float16)exp2f(0.8f * s1 * L2E);
  h16x8 es80 = {e80, e80, e80, e80, e80, e80, e80, e80};
  h16x8 es81 = {e81, e81, e81, e81, e81, e81, e81, e81};

  f32x4 acc[2][4] = {};
  f32x4 accd[2] = {};
  const h16x8 ones = {(_Float16)1.f, (_Float16)1.f, (_Float16)1.f, (_Float16)1.f,
                      (_Float16)1.f, (_Float16)1.f, (_Float16)1.f, (_Float16)1.f};

  const u32* ab0 = Abt + (size_t)(q * 64) * NN + n0 + col;        // +it*NN
  const u32* ab1 = ab0 + 16;
  const _Float16* edp = edh + (size_t)h * MM + q * 2048 + qs;     // +it*32
  const _Float16* e2p = ed2h + (size_t)h * MM + q * 2048 + qs;
  const uint4* bp = Bp + ((size_t)h * 256 + q * 64) * 256 + lane; // +it*256+dt*64

  // pipeline stage registers: iter 0 preloaded
  u32 aw0 = ab0[0], aw1 = ab1[0];
  h16x8 edv = *(const h16x8*)edp;
  h16x8 e2v = *(const h16x8*)e2p;
  uint4 bu0 = bp[0], bu1 = bp[64], bu2 = bp[128], bu3 = bp[192];

  for (int it = 0; it < 64; ++it) {
    // issue iter it+1 loads before consuming iter it
    u32 naw0 = 0, naw1 = 0;
    h16x8 nedv = {}, ne2v = {};
    uint4 nb0 = {}, nb1 = {}, nb2 = {}, nb3 = {};
    if (it < 63) {
      naw0 = ab0[(size_t)(it + 1) * NN];
      naw1 = ab1[(size_t)(it + 1) * NN];
      nedv = *(const h16x8*)(edp + (it + 1) * 32);
      ne2v = *(const h16x8*)(e2p + (it + 1) * 32);
      nb0 = bp[(it + 1) * 256];
      nb1 = bp[(it + 1) * 256 + 64];
      nb2 = bp[(it + 1) * 256 + 128];
      nb3 = bp[(it + 1) * 256 + 192];
    }

    uint4 m0 = LUT[(aw0 >> qs) & 0xff];
    uint4 m1 = LUT[(aw1 >> qs) & 0xff];
    union { h16x8 v; uint4 u; } w0, w1, b0, b1, b2, b3;
    b0.u = bu0; b1.u = bu1; b2.u = bu2; b3.u = bu3;
    w0.v = __builtin_elementwise_max(edv * es80, e2v);
    w1.v = __builtin_elementwise_max(edv * es81, e2v);
    w0.u.x &= m0.x; w0.u.y &= m0.y; w0.u.z &= m0.z; w0.u.w &= m0.w;
    w1.u.x &= m1.x; w1.u.y &= m1.y; w1.u.z &= m1.z; w1.u.w &= m1.w;

    acc[0][0] = __builtin_amdgcn_mfma_f32_16x16x32_f16(w0.v, b0.v, acc[0][0], 0, 0, 0);
    acc[1][0] = __builtin_amdgcn_mfma_f32_16x16x32_f16(w1.v, b0.v, acc[1][0], 0, 0, 0);
    acc[0][1] = __builtin_amdgcn_mfma_f32_16x16x32_f16(w0.v, b1.v, acc[0][1], 0, 0, 0);
    acc[1][1] = __builtin_amdgcn_mfma_f32_16x16x32_f16(w1.v, b1.v, acc[1][1], 0, 0, 0);
    acc[0][2] = __builtin_amdgcn_mfma_f32_16x16x32_f16(w0.v, b2.v, acc[0][2], 0, 0, 0);
    acc[1][2] = __builtin_amdgcn_mfma_f32_16x16x32_f16(w1.v, b2.v, acc[1][2], 0, 0, 0);
    acc[0][3] = __builtin_amdgcn_mfma_f32_16x16x32_f16(w0.v, b3.v, acc[0][3], 0, 0, 0);
    acc[1][3] = __builtin_amdgcn_mfma_f32_16x16x32_f16(w1.v, b3.v, acc[1][3], 0, 0, 0);
    accd[0] = __builtin_amdgcn_mfma_f32_16x16x32_f16(w0.v, ones, accd[0], 0, 0, 0);
    accd[1] = __builtin_amdgcn_mfma_f32_16x16x32_f16(w1.v, ones, accd[1], 0, 0, 0);

    aw0 = naw0; aw1 = naw1; edv = nedv; e2v = ne2v;
    bu0 = nb0; bu1 = nb1; bu2 = nb2; bu3 = nb3;
  }

  // Reduce quarters/rows via LDS float atomics (ds_add), once per block.
  float* Hh = Hsum + h * 2048;
#pragma unroll
  for (int rt = 0; rt < 2; ++rt) {
#pragma unroll
    for (int dt = 0; dt < 4; ++dt)
#pragma unroll
      for (int r2 = 0; r2 < 4; ++r2)
        atomicAdd(&Hh[(rt * 16 + quad * 4 + r2) * 64 + dt * 16 + col],
                  acc[rt][dt][r2]);
    if (col == 0) {
#pragma unroll
      for (int r2 = 0; r2 < 4; ++r2)
        atomicAdd(&Dsum[h * 32 + rt * 16 + quad * 4 + r2], accd[rt][r2]);
    }
  }
  __syncthreads();

  // Head mean with per-head denom; then per-row softmax.
  for (int i = t; i < 2048; i += 1024) {
    int r = i >> 6;
    float v = 0.f;
#pragma unroll
    for (int hh = 0; hh < 4; ++hh) v += Hsum[hh * 2048 + i] / Dsum[hh * 32 + r];
    hp[i] = 0.25f * v;
  }
  __syncthreads();

#pragma unroll
  for (int i = 0; i < 2; ++i) {
    int r = wv * 2 + i;
    float v = hp[r * 64 + lane];
    float mx = v;
#pragma unroll
    for (int o = 32; o; o >>= 1) mx = fmaxf(mx, __shfl_xor(mx, o));
    float p = exp2f((v - mx) * L2E);
    float sm = p;
#pragma unroll
    for (int o = 32; o; o >>= 1) sm += __shfl_xor(sm, o);
    out[(size_t)(n0 + r) * HD + lane] = p / sm;
  }
}

extern "C" void kernel_launch(void* const* d_in, const int* in_sizes, int n_in,
                              void* d_out, int out_size, void* d_ws, size_t ws_size,
                              hipStream_t stream) {
  const float* F0 = (const float*)d_in[0];
  const float* E0 = (const float*)d_in[1];
  const int* A = (const int*)d_in[2];
  const float* Wf = (const float*)d_in[3];
  const float* We = (const float*)d_in[4];
  const float* a = (const float*)d_in[5];
  float* out = (float*)d_out;

  char* w = (char*)d_ws;
  float* esrc = (float*)w;        w += (size_t)NH * NN * 4;
  _Float16* edh = (_Float16*)w;   w += (size_t)NH * MM * 2;
  _Float16* ed2h = (_Float16*)w;  w += (size_t)NH * MM * 2;
  float* vf = (float*)w;          w += (size_t)NH * FD * 4;
  _Float16* E1T = (_Float16*)w;   w += (size_t)NH * HD * MM * 2;
  uint4* Bp = (uint4*)w;          w += (size_t)NH * HD * MM * 2;
  u32* Abt = (u32*)w;             w += (size_t)(MM / 32) * NN * 4;

  k_vf<<<1, 512, 0, stream>>>(Wf, a, vf);
  k_esrc<<<(NH * NN) / 256, 256, 0, stream>>>(F0, vf, esrc);
  k_e1<<<(NH * MM / 4) / 4, 256, 0, stream>>>(E0, We, a, E1T, edh, ed2h);
  k_abits<<<NN / 4, 256, 0, stream>>>(A, Abt);
  k_pack<<<NH * 256, 256, 0, stream>>>(E1T, Bp);
  k_main<<<NN / NTILE, 1024, 0, stream>>>(Abt, Bp, esrc, edh, ed2h, out);
}

// Round 9
// 485.819 us; speedup vs baseline: 1.2577x; 1.1533x over previous
//
#include <hip/hip_runtime.h>
#include <hip/hip_fp16.h>

#define NN 8192
#define MM 8192
#define FD 128
#define EDm 128
#define HD 64
#define NH 4
#define NTILE 32

typedef float f32x4 __attribute__((ext_vector_type(4)));
typedef _Float16 h16x8 __attribute__((ext_vector_type(8)));
typedef unsigned int u32;

// Fused: per-block recompute of vf[h][f] = Wf[h][f][:].a[h][:], then
// esrc[h][n] = F0[n,:] . vf[h,:]
__global__ void k_esrc(const float* __restrict__ F0, const float* __restrict__ Wf,
                       const float* __restrict__ a, float* __restrict__ esrc) {
  __shared__ float vfL[NH * FD];
  int t = threadIdx.x;  // 256
#pragma unroll
  for (int r = 0; r < 2; ++r) {
    int idx = t + r * 256;            // 512 entries
    int h = idx >> 7, f = idx & 127;
    const float* w = Wf + (size_t)(h * FD + f) * HD;
    const float* av = a + h * HD;
    float s = 0.f;
#pragma unroll
    for (int d = 0; d < HD; ++d) s += w[d] * av[d];
    vfL[idx] = s;
  }
  __syncthreads();
  int g = blockIdx.x * 256 + t;       // 32768
  int n = g >> 2, h = g & 3;
  const float4* fr = (const float4*)(F0 + (size_t)n * FD);
  const float4* vr = (const float4*)(vfL + h * FD);
  float s = 0.f;
#pragma unroll
  for (int i = 0; i < FD / 4; ++i) {
    float4 x = fr[i], y = vr[i];
    s += x.x * y.x + x.y * y.y + x.z * y.z + x.w * y.w;
  }
  esrc[h * NN + n] = s;
}

// E1 = E0·We per head; writes Bp directly in MFMA-B fragment order
// (wave = 8 m-rows, lane = d), plus ed/ed2 fp16 exp tables. No E1T pass.
__global__ void k_e1(const float* __restrict__ E0, const float* __restrict__ We,
                     const float* __restrict__ a, uint4* __restrict__ Bp,
                     _Float16* __restrict__ edh, _Float16* __restrict__ ed2h) {
  int wid = (blockIdx.x * blockDim.x + threadIdx.x) >> 6;  // 4096 waves
  int lane = threadIdx.x & 63;
  int h = wid >> 10;
  int mg = wid & 1023;
  int m = mg * 8;
  const float* we = We + (size_t)h * EDm * HD + lane;
  const float* e0r = E0 + (size_t)m * EDm;
  float ac[8] = {};
#pragma unroll 4
  for (int e = 0; e < EDm; ++e) {
    float wv = we[e * HD];
#pragma unroll
    for (int j = 0; j < 8; ++j) ac[j] += e0r[j * EDm + e] * wv;
  }
  // Bp[h][mc][dt][quad*16+col]: 8 fp16 (m..m+7) at d = dt*16+col
  int mc = mg >> 2, quad = mg & 3, dt = lane >> 4, col = lane & 15;
  union { h16x8 v; uint4 u; } hv;
#pragma unroll
  for (int j = 0; j < 8; ++j) hv.v[j] = (_Float16)ac[j];
  Bp[(((size_t)h * 256 + mc) * 4 + dt) * 64 + quad * 16 + col] = hv.u;

  float av = a[h * HD + lane];
  float d[8];
#pragma unroll
  for (int j = 0; j < 8; ++j) d[j] = ac[j] * av;
#pragma unroll
  for (int o = 32; o; o >>= 1)
#pragma unroll
    for (int j = 0; j < 8; ++j) d[j] += __shfl_xor(d[j], o);
  if (lane == 0) {
    const float L2E = 1.4426950408889634f;
    union { h16x8 v; uint4 u; } e1, e2;
#pragma unroll
    for (int j = 0; j < 8; ++j) {
      e1.v[j] = (_Float16)exp2f(d[j] * L2E);
      e2.v[j] = (_Float16)exp2f(0.2f * d[j] * L2E);
    }
    *(uint4*)(edh + (size_t)h * MM + m) = e1.u;
    *(uint4*)(ed2h + (size_t)h * MM + m) = e2.u;
  }
}

// bit b0 at `bit`, b1 at bit+1 -> (b0?0xffff:0)|(b1?0xffff0000:0)
__device__ __forceinline__ u32 hm2b(u32 w, int bit) {
  return (((w >> bit) & 1u) | (((w >> (bit + 1)) & 1u) << 16)) * 0xffffu;
}

// Main: 256 blocks x 1024 thr. Phase 0: block ballots its own 32 A-rows into
// LDS bit-words (A read once chip-wide, coalesced nt). Then barrier-free MFMA
// loop: masks via broadcast ds_read + VALU expand; B/ed 1-iter reg pipeline.
// In-block reduce + head-mean + row softmax -> out. 3 kernels total.
__global__ __launch_bounds__(1024, 4) void k_main(
    const int* __restrict__ A, const uint4* __restrict__ Bp,
    const float* __restrict__ esrc, const _Float16* __restrict__ edh,
    const _Float16* __restrict__ ed2h, float* __restrict__ out) {
  __shared__ __align__(16) char smem[41472];
  u32* bits = (u32*)smem;              // [32 rows][257 words] (256 used)
  float* Hsum = (float*)smem;          // epilogue alias: [4][32][64] 32 KB
  float* Dsum = (float*)(smem + 32768);// [4][32]
  float* hp = (float*)(smem + 33280);  // [32][64]

  const int t = threadIdx.x;
  const int lane = t & 63;
  const int wv = t >> 6;       // 0..15
  const int h = wv & 3;        // head
  const int q = wv >> 2;       // m-quarter (2048 m)
  const int col = lane & 15;
  const int quad = lane >> 4;
  const int qs = quad * 8;
  const int n0 = blockIdx.x * NTILE;
  const float L2E = 1.4426950408889634f;

  // ---- phase 0: ballot 2 rows per wave into LDS bits ----
  {
    const int r0 = wv * 2, r1 = r0 + 1;
    const int* a0p = A + (size_t)(n0 + r0) * MM + lane;
    const int* a1p = A + (size_t)(n0 + r1) * MM + lane;
    for (int c8 = 0; c8 < 16; ++c8) {
      int v0[8], v1[8];
#pragma unroll
      for (int k = 0; k < 8; ++k)
        v0[k] = __builtin_nontemporal_load(a0p + (c8 * 8 + k) * 64);
#pragma unroll
      for (int k = 0; k < 8; ++k)
        v1[k] = __builtin_nontemporal_load(a1p + (c8 * 8 + k) * 64);
#pragma unroll
      for (int k = 0; k < 8; ++k) {
        int c = c8 * 8 + k;
        unsigned long long b = __ballot(v0[k] > 0);
        if (lane == 0) bits[r0 * 257 + 2 * c] = (u32)b;
        if (lane == 32) bits[r0 * 257 + 2 * c + 1] = (u32)(b >> 32);
      }
#pragma unroll
      for (int k = 0; k < 8; ++k) {
        int c = c8 * 8 + k;
        unsigned long long b = __ballot(v1[k] > 0);
        if (lane == 0) bits[r1 * 257 + 2 * c] = (u32)b;
        if (lane == 32) bits[r1 * 257 + 2 * c + 1] = (u32)(b >> 32);
      }
    }
  }
  __syncthreads();

  // ---- main loop ----
  float s0 = esrc[h * NN + n0 + col];
  float s1 = esrc[h * NN + n0 + 16 + col];
  _Float16 e80 = (_Float16)exp2f(0.8f * s0 * L2E);
  _Float16 e81 = (_Float16)exp2f(0.8f * s1 * L2E);
  h16x8 es80 = {e80, e80, e80, e80, e80, e80, e80, e80};
  h16x8 es81 = {e81, e81, e81, e81, e81, e81, e81, e81};

  f32x4 acc[2][4] = {};
  f32x4 accd[2] = {};
  const h16x8 ones = {(_Float16)1.f, (_Float16)1.f, (_Float16)1.f, (_Float16)1.f,
                      (_Float16)1.f, (_Float16)1.f, (_Float16)1.f, (_Float16)1.f};

  const u32* w0p = bits + col * 257 + q * 64;          // +it
  const u32* w1p = bits + (col + 16) * 257 + q * 64;   // +it
  const _Float16* edp = edh + (size_t)h * MM + q * 2048 + qs;   // +it*32
  const _Float16* e2p = ed2h + (size_t)h * MM + q * 2048 + qs;
  const uint4* bp = Bp + ((size_t)h * 256 + q * 64) * 256 + lane; // +it*256+dt*64

  u32 aw0 = w0p[0], aw1 = w1p[0];
  h16x8 edv = *(const h16x8*)edp;
  h16x8 e2v = *(const h16x8*)e2p;
  uint4 bu0 = bp[0], bu1 = bp[64], bu2 = bp[128], bu3 = bp[192];

  for (int it = 0; it < 64; ++it) {
    u32 naw0 = 0, naw1 = 0;
    h16x8 nedv = {}, ne2v = {};
    uint4 nb0 = {}, nb1 = {}, nb2 = {}, nb3 = {};
    if (it < 63) {
      naw0 = w0p[it + 1];
      naw1 = w1p[it + 1];
      nedv = *(const h16x8*)(edp + (it + 1) * 32);
      ne2v = *(const h16x8*)(e2p + (it + 1) * 32);
      nb0 = bp[(it + 1) * 256];
      nb1 = bp[(it + 1) * 256 + 64];
      nb2 = bp[(it + 1) * 256 + 128];
      nb3 = bp[(it + 1) * 256 + 192];
    }

    uint4 m0, m1;
    m0.x = hm2b(aw0, qs);     m0.y = hm2b(aw0, qs + 2);
    m0.z = hm2b(aw0, qs + 4); m0.w = hm2b(aw0, qs + 6);
    m1.x = hm2b(aw1, qs);     m1.y = hm2b(aw1, qs + 2);
    m1.z = hm2b(aw1, qs + 4); m1.w = hm2b(aw1, qs + 6);

    union { h16x8 v; uint4 u; } w0, w1, b0, b1, b2, b3;
    b0.u = bu0; b1.u = bu1; b2.u = bu2; b3.u = bu3;
    w0.v = __builtin_elementwise_max(edv * es80, e2v);
    w1.v = __builtin_elementwise_max(edv * es81, e2v);
    w0.u.x &= m0.x; w0.u.y &= m0.y; w0.u.z &= m0.z; w0.u.w &= m0.w;
    w1.u.x &= m1.x; w1.u.y &= m1.y; w1.u.z &= m1.z; w1.u.w &= m1.w;

    acc[0][0] = __builtin_amdgcn_mfma_f32_16x16x32_f16(w0.v, b0.v, acc[0][0], 0, 0, 0);
    acc[1][0] = __builtin_amdgcn_mfma_f32_16x16x32_f16(w1.v, b0.v, acc[1][0], 0, 0, 0);
    acc[0][1] = __builtin_amdgcn_mfma_f32_16x16x32_f16(w0.v, b1.v, acc[0][1], 0, 0, 0);
    acc[1][1] = __builtin_amdgcn_mfma_f32_16x16x32_f16(w1.v, b1.v, acc[1][1], 0, 0, 0);
    acc[0][2] = __builtin_amdgcn_mfma_f32_16x16x32_f16(w0.v, b2.v, acc[0][2], 0, 0, 0);
    acc[1][2] = __builtin_amdgcn_mfma_f32_16x16x32_f16(w1.v, b2.v, acc[1][2], 0, 0, 0);
    acc[0][3] = __builtin_amdgcn_mfma_f32_16x16x32_f16(w0.v, b3.v, acc[0][3], 0, 0, 0);
    acc[1][3] = __builtin_amdgcn_mfma_f32_16x16x32_f16(w1.v, b3.v, acc[1][3], 0, 0, 0);
    accd[0] = __builtin_amdgcn_mfma_f32_16x16x32_f16(w0.v, ones, accd[0], 0, 0, 0);
    accd[1] = __builtin_amdgcn_mfma_f32_16x16x32_f16(w1.v, ones, accd[1], 0, 0, 0);

    aw0 = naw0; aw1 = naw1; edv = nedv; e2v = ne2v;
    bu0 = nb0; bu1 = nb1; bu2 = nb2; bu3 = nb3;
  }
  __syncthreads();   // bits dead; re-purpose LDS for reduction

  for (int i = t; i < 8320; i += 1024) Hsum[i] = 0.f;  // Hsum + Dsum
  __syncthreads();

  float* Hh = Hsum + h * 2048;
#pragma unroll
  for (int rt = 0; rt < 2; ++rt) {
#pragma unroll
    for (int dt = 0; dt < 4; ++dt)
#pragma unroll
      for (int r2 = 0; r2 < 4; ++r2)
        atomicAdd(&Hh[(rt * 16 + quad * 4 + r2) * 64 + dt * 16 + col],
                  acc[rt][dt][r2]);
    if (col == 0) {
#pragma unroll
      for (int r2 = 0; r2 < 4; ++r2)
        atomicAdd(&Dsum[h * 32 + rt * 16 + quad * 4 + r2], accd[rt][r2]);
    }
  }
  __syncthreads();

  for (int i = t; i < 2048; i += 1024) {
    int r = i >> 6;
    float v = 0.f;
#pragma unroll
    for (int hh = 0; hh < 4; ++hh) v += Hsum[hh * 2048 + i] / Dsum[hh * 32 + r];
    hp[i] = 0.25f * v;
  }
  __syncthreads();

#pragma unroll
  for (int i = 0; i < 2; ++i) {
    int r = wv * 2 + i;
    float v = hp[r * 64 + lane];
    float mx = v;
#pragma unroll
    for (int o = 32; o; o >>= 1) mx = fmaxf(mx, __shfl_xor(mx, o));
    float p = exp2f((v - mx) * L2E);
    float sm = p;
#pragma unroll
    for (int o = 32; o; o >>= 1) sm += __shfl_xor(sm, o);
    out[(size_t)(n0 + r) * HD + lane] = p / sm;
  }
}

extern "C" void kernel_launch(void* const* d_in, const int* in_sizes, int n_in,
                              void* d_out, int out_size, void* d_ws, size_t ws_size,
                              hipStream_t stream) {
  const float* F0 = (const float*)d_in[0];
  const float* E0 = (const float*)d_in[1];
  const int* A = (const int*)d_in[2];
  const float* Wf = (const float*)d_in[3];
  const float* We = (const float*)d_in[4];
  const float* a = (const float*)d_in[5];
  float* out = (float*)d_out;

  char* w = (char*)d_ws;
  float* esrc = (float*)w;        w += (size_t)NH * NN * 4;
  _Float16* edh = (_Float16*)w;   w += (size_t)NH * MM * 2;
  _Float16* ed2h = (_Float16*)w;  w += (size_t)NH * MM * 2;
  uint4* Bp = (uint4*)w;          w += (size_t)NH * HD * MM * 2;

  k_esrc<<<(NH * NN) / 256 / 4, 256, 0, stream>>>(F0, Wf, a, esrc);
  k_e1<<<(NH * MM / 8) / 4, 256, 0, stream>>>(E0, We, a, Bp, edh, ed2h);
  k_main<<<NN / NTILE, 1024, 0, stream>>>(A, Bp, esrc, edh, ed2h, out);
}